// Round 7
// baseline (212.604 us; speedup 1.0000x reference)
//
#include <hip/hip_runtime.h>

// Causal self-attention fwd: B=2,T=2048,C=1024,H=16,D=64, scale=0.1/sqrt(D)
// prep (cast x + transpose weights); qkv GEMM 128x128 w/ global_load_lds +
// XOR swizzle, q-cols pre-scaled by SCALE*log2e; flash attn (MFMA, m=0
// softmax, Q-block 128 w/ K/V frag reuse, double-buffered K/V LDS (1 barrier
// per stage), XCD-affine CU-balanced grid, coalesced epilogue); proj GEMM.

#define Bz 2
#define Tz 2048
#define Cz 1024
#define Hz 16
#define Dz 64
// SCALE * log2(e): q pre-scaled so attn does p = exp2(S) directly
#define QSCALE 0.01803368801111437f

typedef unsigned short u16;
typedef short bf16x8 __attribute__((ext_vector_type(8)));
typedef float f32x4 __attribute__((ext_vector_type(4)));

__device__ inline u16 f2bf(float f) {  // round-half-up: 2 VALU, <=0.5 ulp
  return (u16)((__float_as_uint(f) + 0x8000u) >> 16);
}

__device__ inline float fexp2(float x) {
#if __has_builtin(__builtin_amdgcn_exp2f)
  return __builtin_amdgcn_exp2f(x);
#else
  return exp2f(x);
#endif
}

__device__ inline void gl_lds16(const u16* g, u16* l) {
  __builtin_amdgcn_global_load_lds(
      (const __attribute__((address_space(1))) void*)g,
      (__attribute__((address_space(3))) void*)l, 16, 0, 0);
}

// ------------- prep: cast x->bf16 + transpose/cast both weights -------------
#define NCAST 4096   // (4096*1024/4)/256
#define NTA   3072   // (3072/32)*(1024/32)
__global__ __launch_bounds__(256) void prep_kernel(const float* __restrict__ x,
                                                   const float* __restrict__ wa,
                                                   const float* __restrict__ wp,
                                                   u16* __restrict__ xb,
                                                   u16* __restrict__ waT,
                                                   u16* __restrict__ wpT) {
  const int bx = blockIdx.x, t = threadIdx.x;
  if (bx < NCAST) {
    int i = bx * 256 + t;
    float4 v = ((const float4*)x)[i];
    ushort4 o = {f2bf(v.x), f2bf(v.y), f2bf(v.z), f2bf(v.w)};
    ((ushort4*)xb)[i] = o;
    return;
  }
  __shared__ float tile[32][33];
  const float* W;
  u16* WT;
  int N, idx;
  if (bx < NCAST + NTA) {
    W = wa; WT = waT; N = 3 * Cz; idx = bx - NCAST;
  } else {
    W = wp; WT = wpT; N = Cz; idx = bx - NCAST - NTA;
  }
  const int n0 = (idx % (N / 32)) * 32, k0 = (idx / (N / 32)) * 32;
  const int tx = t & 31, ty = t >> 5;  // (32, 8)
#pragma unroll
  for (int i = 0; i < 4; ++i)
    tile[ty + 8 * i][tx] = W[(size_t)(k0 + ty + 8 * i) * N + n0 + tx];
  __syncthreads();
#pragma unroll
  for (int i = 0; i < 4; ++i)
    WT[(size_t)(n0 + ty + 8 * i) * Cz + k0 + tx] = f2bf(tile[tx][ty + 8 * i]);
}

// ---------- C[M][N] = A[M][K]*BT[N][K]^T + bias; 128xTN tile ----------
// cols < qcols get (acc+bias)*qscale (pre-scales q for attn exp2).
template <bool OUT_BF16, int TN>
__global__ __launch_bounds__(256) void gemm_bt(const u16* __restrict__ A,
                                               const u16* __restrict__ BT,
                                               const float* __restrict__ bias,
                                               void* __restrict__ Cout,
                                               int M, int N, int K,
                                               int qcols, float qscale) {
  __shared__ __align__(16) u16 As[128 * 32];
  __shared__ __align__(16) u16 Bs[TN * 32];
  constexpr int NT = TN / 32;
  const int t = threadIdx.x;
  const int wave = t >> 6, lane = t & 63;
  const int lm = lane & 15, lg = lane >> 4;
  const int wm = wave >> 1, wn = wave & 1;
  const int m0 = blockIdx.y * 128, n0 = blockIdx.x * TN;

  const int srow_in = lane >> 2;
  const int gseg = (lane & 3) ^ ((lane >> 3) & 3);  // XOR col-seg swizzle
  const size_t a_off0 = (size_t)(m0 + 32 * wave + srow_in) * K + gseg * 8;
  const size_t a_off1 = a_off0 + 16 * (size_t)K;
  u16* asl0 = &As[(32 * wave) * 32];
  u16* asl1 = &As[(32 * wave + 16) * 32];
  size_t b_off0 = 0, b_off1 = 0;
  u16 *bsl0, *bsl1 = nullptr;
  if constexpr (TN == 128) {
    b_off0 = (size_t)(n0 + 32 * wave + srow_in) * K + gseg * 8;
    b_off1 = b_off0 + 16 * (size_t)K;
    bsl0 = &Bs[(32 * wave) * 32];
    bsl1 = &Bs[(32 * wave + 16) * 32];
  } else {
    b_off0 = (size_t)(n0 + 16 * wave + srow_in) * K + gseg * 8;
    bsl0 = &Bs[(16 * wave) * 32];
  }
  const int rseg = (lg ^ ((lm >> 1) & 3)) * 8;

  f32x4 acc[4][NT];
#pragma unroll
  for (int mt = 0; mt < 4; ++mt)
#pragma unroll
    for (int nt = 0; nt < NT; ++nt)
#pragma unroll
      for (int i = 0; i < 4; ++i) acc[mt][nt][i] = 0.f;

  for (int k0 = 0; k0 < K; k0 += 32) {
    __syncthreads();
    gl_lds16(A + a_off0 + k0, asl0);
    gl_lds16(A + a_off1 + k0, asl1);
    gl_lds16(BT + b_off0 + k0, bsl0);
    if constexpr (TN == 128) gl_lds16(BT + b_off1 + k0, bsl1);
    __syncthreads();

    bf16x8 af[4], bfr[NT];
#pragma unroll
    for (int mt = 0; mt < 4; ++mt)
      af[mt] = *(const bf16x8*)&As[(64 * wm + 16 * mt + lm) * 32 + rseg];
#pragma unroll
    for (int nt = 0; nt < NT; ++nt)
      bfr[nt] = *(const bf16x8*)&Bs[((TN / 2) * wn + 16 * nt + lm) * 32 + rseg];
#pragma unroll
    for (int mt = 0; mt < 4; ++mt)
#pragma unroll
      for (int nt = 0; nt < NT; ++nt)
        acc[mt][nt] = __builtin_amdgcn_mfma_f32_16x16x32_bf16(af[mt], bfr[nt],
                                                              acc[mt][nt], 0, 0, 0);
  }

#pragma unroll
  for (int nt = 0; nt < NT; ++nt) {
    int gc = n0 + (TN / 2) * wn + 16 * nt + lm;
    float bv = bias[gc];
    float sc = (gc < qcols) ? qscale : 1.f;
#pragma unroll
    for (int mt = 0; mt < 4; ++mt) {
#pragma unroll
      for (int i = 0; i < 4; ++i) {
        int gr = m0 + 64 * wm + 16 * mt + 4 * lg + i;
        float v = (acc[mt][nt][i] + bv) * sc;
        if (OUT_BF16)
          ((u16*)Cout)[(size_t)gr * N + gc] = f2bf(v);
        else
          ((float*)Cout)[(size_t)gr * N + gc] = v;
      }
    }
  }
}

// ---------------- flash attention, MFMA bf16, m=0 softmax ----------------
// Q-block 128: wave w owns rows q0+64*rt+16w (rt=0,1); K/V frags read from
// LDS once per stage, reused for both rt -> LDS reads/unit-work ~halved.
// Double-buffered Ks/Vt: ONE barrier per stage; write of tile kt+1 overlaps
// compute of tile kt. 1D grid 512: x = qtp*32+bh (XCD-affine); balanced map
// qt = qtp<8 ? qtp : 23-qtp -> every CU class gets 34 kv-tiles; the 2 blocks
// per CU share (b,h) -> L2 K/V locality. p=exp2(S) (q pre-scaled), l
// deferred. Ps (single, wave-private rows) reused rt0 then rt1 (DS ops are
// FIFO per wave). Coalesced 16B epilogue via Ps bounce.
__global__ __launch_bounds__(256) void attn_kernel(const u16* __restrict__ qkv,
                                                   u16* __restrict__ yb) {
  __shared__ __align__(16) u16 Ks[2][64][72];
  __shared__ __align__(16) u16 Vt[2][64][72];
  __shared__ __align__(16) u16 Ps[64][72];

  const int t = threadIdx.x;
  const int wave = t >> 6, lane = t & 63;
  const int lm = lane & 15, lg = lane >> 4;
  const int kg8 = lg << 3;
  const int x = blockIdx.x;
  const int bh = x & 31, qtp = x >> 5;           // qtp 0..15
  const int qt = (qtp < 8) ? qtp : 23 - qtp;     // CU-balanced map
  const int b = bh >> 4, h = bh & 15;
  const int q0 = qt * 128;
  const int ktmax = 2 * qt + 1;                  // >= 1 always
  const size_t rowstride = 3 * Cz;
  const u16* qbase = qkv + (size_t)b * Tz * rowstride + h * Dz;

  // Q fragments (A-layout): rt half, row q0+64rt+16w+lm
  bf16x8 qf[2][2];
#pragma unroll
  for (int rt = 0; rt < 2; ++rt) {
    const u16* qrow = qbase + (size_t)(q0 + 64 * rt + 16 * wave + lm) * rowstride + kg8;
    qf[rt][0] = *(const bf16x8*)qrow;
    qf[rt][1] = *(const bf16x8*)(qrow + 32);
  }

  float psum[2][4];
  f32x4 Oa[2][4];
#pragma unroll
  for (int rt = 0; rt < 2; ++rt)
#pragma unroll
    for (int i = 0; i < 4; ++i) {
      psum[rt][i] = 0.f;
#pragma unroll
      for (int j = 0; j < 4; ++j) Oa[rt][i][j] = 0.f;
    }

  // staging offsets
  const int ksr = t >> 2, kds = (t & 3) << 4;   // K: row, 16-col seg
  const int vsp = t & 31, vds = (t >> 5) << 3;  // V: s-pair, 8-d seg
  const u16* kbase = qbase + Cz + (size_t)ksr * rowstride + kds;
  const u16* vbase = qbase + 2 * Cz + (size_t)(2 * vsp) * rowstride + vds;
  const size_t tilestep = 64 * rowstride;

  auto load_tile = [&](int kt, uint4 (&kr)[2], uint4 (&vr)[2]) {
    const u16* kp = kbase + (size_t)kt * tilestep;
    const u16* vp = vbase + (size_t)kt * tilestep;
    kr[0] = *(const uint4*)kp;
    kr[1] = *(const uint4*)(kp + 8);
    vr[0] = *(const uint4*)vp;
    vr[1] = *(const uint4*)(vp + rowstride);
  };
  auto stage_write = [&](int buf, const uint4 (&kr)[2], const uint4 (&vr)[2]) {
    *(uint4*)&Ks[buf][ksr][kds] = kr[0];
    *(uint4*)&Ks[buf][ksr][kds + 8] = kr[1];
    unsigned av[4] = {vr[0].x, vr[0].y, vr[0].z, vr[0].w};
    unsigned cv[4] = {vr[1].x, vr[1].y, vr[1].z, vr[1].w};
#pragma unroll
    for (int j = 0; j < 4; ++j) {
      unsigned w0 = (av[j] & 0xffffu) | (cv[j] << 16);
      unsigned w1 = (av[j] >> 16) | (cv[j] & 0xffff0000u);
      *(unsigned*)&Vt[buf][vds + 2 * j][2 * vsp] = w0;
      *(unsigned*)&Vt[buf][vds + 2 * j + 1][2 * vsp] = w1;
    }
  };

  // prologue: tile 0 -> buf0; tile 1 pending in regs
  uint4 kr[2], vr[2];
  load_tile(0, kr, vr);
  stage_write(0, kr, vr);
  load_tile(1, kr, vr);

  for (int kt = 0; kt <= ktmax; ++kt) {
    __syncthreads();  // buf(kt&1) writes visible; buf((kt+1)&1) readers done
    if (kt + 1 <= ktmax) {
      stage_write((kt + 1) & 1, kr, vr);
      if (kt + 2 <= ktmax) load_tile(kt + 2, kr, vr);
    }
    const int cb = kt & 1;

    // ---- K/V fragments: read once, reuse for both rt ----
    bf16x8 kf0[4], kf1[4], vf0[4], vf1[4];
#pragma unroll
    for (int c = 0; c < 4; ++c) {
      kf0[c] = *(const bf16x8*)&Ks[cb][c * 16 + lm][kg8];
      kf1[c] = *(const bf16x8*)&Ks[cb][c * 16 + lm][32 + kg8];
      vf0[c] = *(const bf16x8*)&Vt[cb][c * 16 + lm][kg8];
      vf1[c] = *(const bf16x8*)&Vt[cb][c * 16 + lm][32 + kg8];
    }

#pragma unroll
    for (int rt = 0; rt < 2; ++rt) {
      if (kt > 2 * qt + rt) continue;  // rt=0 inactive only at kt==ktmax
      const bool diag = (kt == 2 * qt + rt);

      // ---- S = Q K^T (pre-scaled) ----
      f32x4 S[4];
#pragma unroll
      for (int c = 0; c < 4; ++c) {
        f32x4 s;
#pragma unroll
        for (int i = 0; i < 4; ++i) s[i] = 0.f;
        s = __builtin_amdgcn_mfma_f32_16x16x32_bf16(qf[rt][0], kf0[c], s, 0, 0, 0);
        s = __builtin_amdgcn_mfma_f32_16x16x32_bf16(qf[rt][1], kf1[c], s, 0, 0, 0);
        S[c] = s;
      }

      // ---- p = exp2(S), diag mask, accumulate l, write P ----
#pragma unroll
      for (int c = 0; c < 4; ++c) {
#pragma unroll
        for (int r = 0; r < 4; ++r) {
          float p = fexp2(S[c][r]);
          if (diag && (c * 16 + lm) > (16 * wave + 4 * lg + r)) p = 0.f;
          psum[rt][r] += p;
          Ps[16 * wave + 4 * lg + r][c * 16 + lm] = f2bf(p);
        }
      }

      // ---- O += P V (Ps rows wave-private; DS FIFO per wave) ----
      bf16x8 pf0 = *(const bf16x8*)&Ps[16 * wave + lm][kg8];
      bf16x8 pf1 = *(const bf16x8*)&Ps[16 * wave + lm][32 + kg8];
#pragma unroll
      for (int c = 0; c < 4; ++c) {
        Oa[rt][c] = __builtin_amdgcn_mfma_f32_16x16x32_bf16(pf0, vf0[c], Oa[rt][c], 0, 0, 0);
        Oa[rt][c] = __builtin_amdgcn_mfma_f32_16x16x32_bf16(pf1, vf1[c], Oa[rt][c], 0, 0, 0);
      }
    }
  }

  // ---- epilogue: l-reduction, normalize, bounce via Ps, coalesced store ----
#pragma unroll
  for (int rt = 0; rt < 2; ++rt) {
    float inv[4];
#pragma unroll
    for (int r = 0; r < 4; ++r) {
      float s = psum[rt][r];
#pragma unroll
      for (int msk = 1; msk < 16; msk <<= 1) s += __shfl_xor(s, msk);
      inv[r] = 1.f / s;
    }
#pragma unroll
    for (int c = 0; c < 4; ++c)
#pragma unroll
      for (int r = 0; r < 4; ++r)
        Ps[16 * wave + 4 * lg + r][c * 16 + lm] = f2bf(Oa[rt][c][r] * inv[r]);

    const int row = lane >> 2, seg = lane & 3;
    const uint4* src = (const uint4*)&Ps[16 * wave + row][seg * 16];
    uint4 v0 = src[0];
    uint4 v1 = src[1];
    u16* dst = yb + (size_t)(b * Tz + q0 + 64 * rt + 16 * wave + row) * Cz +
               h * Dz + seg * 16;
    *(uint4*)dst = v0;
    *(uint4*)(dst + 8) = v1;
  }
}

extern "C" void kernel_launch(void* const* d_in, const int* in_sizes, int n_in,
                              void* d_out, int out_size, void* d_ws, size_t ws_size,
                              hipStream_t stream) {
  const float* x      = (const float*)d_in[0];
  const float* w_attn = (const float*)d_in[1];
  const float* b_attn = (const float*)d_in[2];
  const float* w_proj = (const float*)d_in[3];
  const float* b_proj = (const float*)d_in[4];

  char* ws = (char*)d_ws;
  u16* xb   = (u16*)(ws);                        //  8 MB: x bf16 [4096,1024]
  u16* waT  = (u16*)(ws + (8ull << 20));         //  6 MB: w_attn^T bf16 [3072,1024]
  u16* wpT  = (u16*)(ws + (14ull << 20));        //  2 MB: w_proj^T bf16 [1024,1024]
  u16* qkvb = (u16*)(ws + (16ull << 20));        // 24 MB: qkv bf16 (q pre-scaled)
  u16* yb   = (u16*)(ws + (40ull << 20));        //  8 MB: y bf16 [4096,1024]

  const int M = Bz * Tz;  // 4096

  prep_kernel<<<NCAST + NTA + 1024, 256, 0, stream>>>(x, w_attn, w_proj, xb, waT, wpT);
  gemm_bt<true, 128><<<dim3(3 * Cz / 128, M / 128), 256, 0, stream>>>(
      xb, waT, b_attn, qkvb, M, 3 * Cz, Cz, Cz, QSCALE);
  attn_kernel<<<512, 256, 0, stream>>>(qkvb, yb);
  gemm_bt<false, 64><<<dim3(Cz / 64, M / 128), 256, 0, stream>>>(
      yb, wpT, b_proj, d_out, M, Cz, Cz, 0, 1.f);
}

// Round 9
// 212.021 us; speedup vs baseline: 1.0028x; 1.0028x over previous
//
#include <hip/hip_runtime.h>

// Causal self-attention fwd: B=2,T=2048,C=1024,H=16,D=64, scale=0.1/sqrt(D)
// prep (cast x + transpose weights); qkv GEMM 128x128 BK=64 w/ global_load_lds
// + XOR seg swizzle, q pre-scaled by SCALE*log2e; flash attn (MFMA, m=0
// softmax, 2-deep register prefetch, XCD-affine CU-balanced grid, coalesced
// epilogue); proj GEMM 128x64 BK=64.

#define Bz 2
#define Tz 2048
#define Cz 1024
#define Hz 16
#define Dz 64
// SCALE * log2(e): q pre-scaled so attn does p = exp2(S) directly
#define QSCALE 0.01803368801111437f

typedef unsigned short u16;
typedef short bf16x8 __attribute__((ext_vector_type(8)));
typedef float f32x4 __attribute__((ext_vector_type(4)));

#define MFMA32(A, B, C) __builtin_amdgcn_mfma_f32_16x16x32_bf16(A, B, C, 0, 0, 0)

__device__ inline u16 f2bf(float f) {  // round-half-up: 2 VALU, <=0.5 ulp
  return (u16)((__float_as_uint(f) + 0x8000u) >> 16);
}

__device__ inline float fexp2(float x) {
  return exp2f(x);  // maps to v_exp_f32
}

__device__ inline void gl_lds16(const u16* g, u16* l) {
  __builtin_amdgcn_global_load_lds(
      (const __attribute__((address_space(1))) void*)g,
      (__attribute__((address_space(3))) void*)l, 16, 0, 0);
}

// ------------- prep: cast x->bf16 + transpose/cast both weights -------------
#define NCAST 4096   // (4096*1024/4)/256
#define NTA   3072   // (3072/32)*(1024/32)
__global__ __launch_bounds__(256) void prep_kernel(const float* __restrict__ x,
                                                   const float* __restrict__ wa,
                                                   const float* __restrict__ wp,
                                                   u16* __restrict__ xb,
                                                   u16* __restrict__ waT,
                                                   u16* __restrict__ wpT) {
  const int bx = blockIdx.x, t = threadIdx.x;
  if (bx < NCAST) {
    int i = bx * 256 + t;
    float4 v = ((const float4*)x)[i];
    ushort4 o = {f2bf(v.x), f2bf(v.y), f2bf(v.z), f2bf(v.w)};
    ((ushort4*)xb)[i] = o;
    return;
  }
  __shared__ float tile[32][33];
  const float* W;
  u16* WT;
  int N, idx;
  if (bx < NCAST + NTA) {
    W = wa; WT = waT; N = 3 * Cz; idx = bx - NCAST;
  } else {
    W = wp; WT = wpT; N = Cz; idx = bx - NCAST - NTA;
  }
  const int n0 = (idx % (N / 32)) * 32, k0 = (idx / (N / 32)) * 32;
  const int tx = t & 31, ty = t >> 5;  // (32, 8)
#pragma unroll
  for (int i = 0; i < 4; ++i)
    tile[ty + 8 * i][tx] = W[(size_t)(k0 + ty + 8 * i) * N + n0 + tx];
  __syncthreads();
#pragma unroll
  for (int i = 0; i < 4; ++i)
    WT[(size_t)(n0 + ty + 8 * i) * Cz + k0 + tx] = f2bf(tile[tx][ty + 8 * i]);
}

// ---------- C[M][N] = A[M][K]*BT[N][K]^T + bias; 128xTN tile, BK=64 ----------
// Each gl_lds16 stages 8 rows x 64 cols contiguously; lane l -> row +(l>>3),
// LDS seg (l&7), holding GLOBAL seg (l&7)^(l>>3) (swizzle on the global side:
// the LDS dest of global_load_lds is lane-contiguous and can't be scattered).
// Frag read un-swizzles: seg = (lg+4h)^(lm&7). cols < qcols scaled by qscale.
template <bool OUT_BF16, int TN>
__global__ __launch_bounds__(256) void gemm_bt(const u16* __restrict__ A,
                                               const u16* __restrict__ BT,
                                               const float* __restrict__ bias,
                                               void* __restrict__ Cout,
                                               int M, int N, int K,
                                               int qcols, float qscale) {
  __shared__ __align__(16) u16 As[128 * 64];
  __shared__ __align__(16) u16 Bs[TN * 64];
  constexpr int NT = TN / 32;   // n-subtiles per wave (and B staging chunks)
  const int t = threadIdx.x;
  const int wave = t >> 6, lane = t & 63;
  const int lm = lane & 15, lg = lane >> 4;
  const int wm = wave >> 1, wn = wave & 1;
  const int m0 = blockIdx.y * 128, n0 = blockIdx.x * TN;

  const int lrow = lane >> 3;                 // 0..7
  const int gseg = (lane & 7) ^ lrow;         // global col-seg (XOR swizzle)
  const size_t a_base = (size_t)(m0 + 32 * wave + lrow) * K + gseg * 8;
  u16* const a_lds = &As[(32 * wave) * 64];
  const size_t b_base = (size_t)(n0 + (TN / 4) * wave + lrow) * K + gseg * 8;
  u16* const b_lds = &Bs[((TN / 4) * wave) * 64];

  f32x4 acc[4][NT];
#pragma unroll
  for (int mt = 0; mt < 4; ++mt)
#pragma unroll
    for (int nt = 0; nt < NT; ++nt)
#pragma unroll
      for (int i = 0; i < 4; ++i) acc[mt][nt][i] = 0.f;

  for (int k0 = 0; k0 < K; k0 += 64) {
    __syncthreads();
#pragma unroll
    for (int i = 0; i < 4; ++i)
      gl_lds16(A + a_base + (size_t)(8 * i) * K + k0, a_lds + i * 8 * 64);
#pragma unroll
    for (int i = 0; i < NT; ++i)
      gl_lds16(BT + b_base + (size_t)(8 * i) * K + k0, b_lds + i * 8 * 64);
    __syncthreads();

#pragma unroll
    for (int h = 0; h < 2; ++h) {
      const int rs = ((lg + 4 * h) ^ (lm & 7)) * 8;
      bf16x8 af[4], bfr[NT];
#pragma unroll
      for (int mt = 0; mt < 4; ++mt)
        af[mt] = *(const bf16x8*)&As[(64 * wm + 16 * mt + lm) * 64 + rs];
#pragma unroll
      for (int nt = 0; nt < NT; ++nt)
        bfr[nt] = *(const bf16x8*)&Bs[((TN / 2) * wn + 16 * nt + lm) * 64 + rs];
#pragma unroll
      for (int mt = 0; mt < 4; ++mt)
#pragma unroll
        for (int nt = 0; nt < NT; ++nt)
          acc[mt][nt] = MFMA32(af[mt], bfr[nt], acc[mt][nt]);
    }
  }

#pragma unroll
  for (int nt = 0; nt < NT; ++nt) {
    int gc = n0 + (TN / 2) * wn + 16 * nt + lm;
    float bv = bias[gc];
    float sc = (gc < qcols) ? qscale : 1.f;
#pragma unroll
    for (int mt = 0; mt < 4; ++mt) {
#pragma unroll
      for (int i = 0; i < 4; ++i) {
        int gr = m0 + 64 * wm + 16 * mt + 4 * lg + i;
        float v = (acc[mt][nt][i] + bv) * sc;
        if (OUT_BF16)
          ((u16*)Cout)[(size_t)gr * N + gc] = f2bf(v);
        else
          ((float*)Cout)[(size_t)gr * N + gc] = v;
      }
    }
  }
}

// ---------------- flash attention, MFMA bf16, m=0 softmax ----------------
// 1D grid of 1024: x = qtp*32 + bh -> blockIdx%8 == bh%8 (XCD L2 affinity).
// CU-balanced qt map: qt = qtp<16 ? qtp : 47-qtp (every round-robin CU class
// gets 62 kv-tile units). 4 waves; wave w owns Q-rows [64qt+16w,+16). 2-deep
// register prefetch. p = exp2(S) (q pre-scaled), l deferred to epilogue
// butterfly. Epilogue bounces O through wave-private Ps rows for 16B stores.
__global__ __launch_bounds__(256) void attn_kernel(const u16* __restrict__ qkv,
                                                   u16* __restrict__ yb) {
  __shared__ __align__(16) u16 Ks[64][72];
  __shared__ __align__(16) u16 Vt[64][72];
  __shared__ __align__(16) u16 Ps[64][72];

  const int t = threadIdx.x;
  const int wave = t >> 6, lane = t & 63;
  const int lm = lane & 15, lg = lane >> 4;
  const int kg8 = lg << 3;
  const int x = blockIdx.x;
  const int bh = x & 31, qtp = x >> 5;
  const int qt = (qtp < 16) ? qtp : 47 - qtp;  // CU-balanced map
  const int b = bh >> 4, h = bh & 15;
  const int q0 = qt * 64;
  const size_t rowstride = 3 * Cz;
  const u16* qbase = qkv + (size_t)b * Tz * rowstride + h * Dz;

  bf16x8 qf[2];
  {
    const u16* qrow = qbase + (size_t)(q0 + wave * 16 + lm) * rowstride + kg8;
    qf[0] = *(const bf16x8*)qrow;
    qf[1] = *(const bf16x8*)(qrow + 32);
  }

  float psum[4];
  f32x4 Oa[4];
#pragma unroll
  for (int i = 0; i < 4; ++i) {
    psum[i] = 0.f;
#pragma unroll
    for (int j = 0; j < 4; ++j) Oa[i][j] = 0.f;
  }

  // per-thread staging offsets
  const int ksr = t >> 2, kds = (t & 3) << 4;   // K: row, 16-col seg
  const int vsp = t & 31, vds = (t >> 5) << 3;  // V: s-pair, 8-d seg
  const u16* kbase = qbase + Cz + (size_t)ksr * rowstride + kds;
  const u16* vbase = qbase + 2 * Cz + (size_t)(2 * vsp) * rowstride + vds;
  const size_t tilestep = 64 * rowstride;

  uint4 krA[2], vrA[2], krB[2], vrB[2];
  {  // prologue: prefetch tiles 0 and min(1,qt)
    krA[0] = *(const uint4*)kbase;
    krA[1] = *(const uint4*)(kbase + 8);
    vrA[0] = *(const uint4*)vbase;
    vrA[1] = *(const uint4*)(vbase + rowstride);
    const size_t t1 = (qt >= 1) ? tilestep : 0;
    krB[0] = *(const uint4*)(kbase + t1);
    krB[1] = *(const uint4*)(kbase + t1 + 8);
    vrB[0] = *(const uint4*)(vbase + t1);
    vrB[1] = *(const uint4*)(vbase + t1 + rowstride);
  }

  auto stage = [&](uint4 (&kr)[2], uint4 (&vr)[2], int ktc) {
    __syncthreads();  // prior stage's Ks/Vt reads complete
    *(uint4*)&Ks[ksr][kds] = kr[0];
    *(uint4*)&Ks[ksr][kds + 8] = kr[1];
    {
      unsigned av[4] = {vr[0].x, vr[0].y, vr[0].z, vr[0].w};
      unsigned cv[4] = {vr[1].x, vr[1].y, vr[1].z, vr[1].w};
#pragma unroll
      for (int j = 0; j < 4; ++j) {
        unsigned w0 = (av[j] & 0xffffu) | (cv[j] << 16);
        unsigned w1 = (av[j] >> 16) | (cv[j] & 0xffff0000u);
        *(unsigned*)&Vt[vds + 2 * j][2 * vsp] = w0;
        *(unsigned*)&Vt[vds + 2 * j + 1][2 * vsp] = w1;
      }
    }
    __syncthreads();

    // prefetch tile ktc+2 into this stage's regs (overlaps compute)
    if (ktc + 2 <= qt) {
      const u16* kp = kbase + (size_t)(ktc + 2) * tilestep;
      const u16* vp = vbase + (size_t)(ktc + 2) * tilestep;
      kr[0] = *(const uint4*)kp;
      kr[1] = *(const uint4*)(kp + 8);
      vr[0] = *(const uint4*)vp;
      vr[1] = *(const uint4*)(vp + rowstride);
    }

    // ---- S = Q K^T (pre-scaled) ----
    f32x4 S[4];
#pragma unroll
    for (int c = 0; c < 4; ++c) {
      bf16x8 k0 = *(const bf16x8*)&Ks[c * 16 + lm][kg8];
      bf16x8 k1 = *(const bf16x8*)&Ks[c * 16 + lm][32 + kg8];
      f32x4 s;
#pragma unroll
      for (int i = 0; i < 4; ++i) s[i] = 0.f;
      s = MFMA32(qf[0], k0, s);
      s = MFMA32(qf[1], k1, s);
      S[c] = s;
    }

    // ---- p = exp2(S), diag mask, accumulate l, write P ----
    const bool diag = (ktc == qt);
#pragma unroll
    for (int c = 0; c < 4; ++c) {
#pragma unroll
      for (int r = 0; r < 4; ++r) {
        float p = fexp2(S[c][r]);
        if (diag && (c * 16 + lm) > (16 * wave + 4 * lg + r)) p = 0.f;
        psum[r] += p;
        Ps[16 * wave + 4 * lg + r][c * 16 + lm] = f2bf(p);
      }
    }

    // ---- O += P V ----
    bf16x8 pf0 = *(const bf16x8*)&Ps[16 * wave + lm][kg8];
    bf16x8 pf1 = *(const bf16x8*)&Ps[16 * wave + lm][32 + kg8];
#pragma unroll
    for (int c = 0; c < 4; ++c) {
      bf16x8 v0 = *(const bf16x8*)&Vt[c * 16 + lm][kg8];
      bf16x8 v1 = *(const bf16x8*)&Vt[c * 16 + lm][32 + kg8];
      Oa[c] = MFMA32(pf0, v0, Oa[c]);
      Oa[c] = MFMA32(pf1, v1, Oa[c]);
    }
  };

  for (int kt = 0; kt <= qt; kt += 2) {
    stage(krA, vrA, kt);
    if (kt + 1 <= qt) stage(krB, vrB, kt + 1);
  }

  // ---- epilogue: l-reduction, normalize, bounce via Ps, coalesced store ----
  float inv[4];
#pragma unroll
  for (int r = 0; r < 4; ++r) {
    float s = psum[r];
#pragma unroll
    for (int msk = 1; msk < 16; msk <<= 1) s += __shfl_xor(s, msk);
    inv[r] = 1.f / s;
  }
  // Ps rows [16w,16w+16) are wave-private: no barrier needed
#pragma unroll
  for (int c = 0; c < 4; ++c)
#pragma unroll
    for (int r = 0; r < 4; ++r)
      Ps[16 * wave + 4 * lg + r][c * 16 + lm] = f2bf(Oa[c][r] * inv[r]);

  {
    const int row = lane >> 2, seg = lane & 3;
    const uint4* src = (const uint4*)&Ps[16 * wave + row][seg * 16];
    uint4 v0 = src[0];
    uint4 v1 = src[1];
    u16* dst = yb + (size_t)(b * Tz + q0 + 16 * wave + row) * Cz + h * Dz + seg * 16;
    *(uint4*)dst = v0;
    *(uint4*)(dst + 8) = v1;
  }
}

extern "C" void kernel_launch(void* const* d_in, const int* in_sizes, int n_in,
                              void* d_out, int out_size, void* d_ws, size_t ws_size,
                              hipStream_t stream) {
  const float* x      = (const float*)d_in[0];
  const float* w_attn = (const float*)d_in[1];
  const float* b_attn = (const float*)d_in[2];
  const float* w_proj = (const float*)d_in[3];
  const float* b_proj = (const float*)d_in[4];

  char* ws = (char*)d_ws;
  u16* xb   = (u16*)(ws);                        //  8 MB: x bf16 [4096,1024]
  u16* waT  = (u16*)(ws + (8ull << 20));         //  6 MB: w_attn^T bf16 [3072,1024]
  u16* wpT  = (u16*)(ws + (14ull << 20));        //  2 MB: w_proj^T bf16 [1024,1024]
  u16* qkvb = (u16*)(ws + (16ull << 20));        // 24 MB: qkv bf16 (q pre-scaled)
  u16* yb   = (u16*)(ws + (40ull << 20));        //  8 MB: y bf16 [4096,1024]

  const int M = Bz * Tz;  // 4096

  prep_kernel<<<NCAST + NTA + 1024, 256, 0, stream>>>(x, w_attn, w_proj, xb, waT, wpT);
  gemm_bt<true, 128><<<dim3(3 * Cz / 128, M / 128), 256, 0, stream>>>(
      xb, waT, b_attn, qkvb, M, 3 * Cz, Cz, Cz, QSCALE);
  attn_kernel<<<1024, 256, 0, stream>>>(qkvb, yb);
  gemm_bt<false, 64><<<dim3(Cz / 64, M / 128), 256, 0, stream>>>(
      yb, wpT, b_proj, d_out, M, Cz, Cz, 0, 1.f);
}

// Round 10
// 207.879 us; speedup vs baseline: 1.0227x; 1.0199x over previous
//
#include <hip/hip_runtime.h>

// Causal self-attention fwd: B=2,T=2048,C=1024,H=16,D=64, scale=0.1/sqrt(D)
// prep (cast x + transpose weights); qkv GEMM 128x128 BK=64 w/ global_load_lds
// + XOR seg swizzle, q pre-scaled by SCALE*log2e; flash attn (S^T = K*Q^T so
// P stays in registers as 16x16x16-MFMA A-frags -- no Ps LDS; m=0 softmax;
// 2-deep register prefetch; XCD-affine CU-balanced grid); proj GEMM.

#define Bz 2
#define Tz 2048
#define Cz 1024
#define Hz 16
#define Dz 64
// SCALE * log2(e): q pre-scaled so attn does p = exp2(S) directly
#define QSCALE 0.01803368801111437f

typedef unsigned short u16;
typedef short bf16x4 __attribute__((ext_vector_type(4)));
typedef short bf16x8 __attribute__((ext_vector_type(8)));
typedef float f32x4 __attribute__((ext_vector_type(4)));

#define MFMA32(A, B, C) __builtin_amdgcn_mfma_f32_16x16x32_bf16(A, B, C, 0, 0, 0)

// K=16 bf16 MFMA. Host pass never codegens device builtins -- guard with
// __HIP_DEVICE_COMPILE__ (R8 lesson: __has_builtin is false in the host pass).
__device__ inline f32x4 mfma16(bf16x4 a, bf16x4 b, f32x4 c) {
#if defined(__HIP_DEVICE_COMPILE__)
  return __builtin_amdgcn_mfma_f32_16x16x16bf16_1k(a, b, c, 0, 0, 0);
#else
  return c;  // host pass placeholder, never executed
#endif
}

__device__ inline u16 f2bf(float f) {  // round-half-up: 2 VALU, <=0.5 ulp
  return (u16)((__float_as_uint(f) + 0x8000u) >> 16);
}

__device__ inline float fexp2(float x) {  // proven R6 pattern (raw v_exp_f32)
#if __has_builtin(__builtin_amdgcn_exp2f)
  return __builtin_amdgcn_exp2f(x);
#else
  return exp2f(x);
#endif
}

__device__ inline void gl_lds16(const u16* g, u16* l) {
  __builtin_amdgcn_global_load_lds(
      (const __attribute__((address_space(1))) void*)g,
      (__attribute__((address_space(3))) void*)l, 16, 0, 0);
}

// ------------- prep: cast x->bf16 + transpose/cast both weights -------------
#define NCAST 4096   // (4096*1024/4)/256
#define NTA   3072   // (3072/32)*(1024/32)
__global__ __launch_bounds__(256) void prep_kernel(const float* __restrict__ x,
                                                   const float* __restrict__ wa,
                                                   const float* __restrict__ wp,
                                                   u16* __restrict__ xb,
                                                   u16* __restrict__ waT,
                                                   u16* __restrict__ wpT) {
  const int bx = blockIdx.x, t = threadIdx.x;
  if (bx < NCAST) {
    int i = bx * 256 + t;
    float4 v = ((const float4*)x)[i];
    ushort4 o = {f2bf(v.x), f2bf(v.y), f2bf(v.z), f2bf(v.w)};
    ((ushort4*)xb)[i] = o;
    return;
  }
  __shared__ float tile[32][33];
  const float* W;
  u16* WT;
  int N, idx;
  if (bx < NCAST + NTA) {
    W = wa; WT = waT; N = 3 * Cz; idx = bx - NCAST;
  } else {
    W = wp; WT = wpT; N = Cz; idx = bx - NCAST - NTA;
  }
  const int n0 = (idx % (N / 32)) * 32, k0 = (idx / (N / 32)) * 32;
  const int tx = t & 31, ty = t >> 5;  // (32, 8)
#pragma unroll
  for (int i = 0; i < 4; ++i)
    tile[ty + 8 * i][tx] = W[(size_t)(k0 + ty + 8 * i) * N + n0 + tx];
  __syncthreads();
#pragma unroll
  for (int i = 0; i < 4; ++i)
    WT[(size_t)(n0 + ty + 8 * i) * Cz + k0 + tx] = f2bf(tile[tx][ty + 8 * i]);
}

// ---------- C[M][N] = A[M][K]*BT[N][K]^T + bias; 128xTN tile, BK=64 ----------
template <bool OUT_BF16, int TN>
__global__ __launch_bounds__(256) void gemm_bt(const u16* __restrict__ A,
                                               const u16* __restrict__ BT,
                                               const float* __restrict__ bias,
                                               void* __restrict__ Cout,
                                               int M, int N, int K,
                                               int qcols, float qscale) {
  __shared__ __align__(16) u16 As[128 * 64];
  __shared__ __align__(16) u16 Bs[TN * 64];
  constexpr int NT = TN / 32;
  const int t = threadIdx.x;
  const int wave = t >> 6, lane = t & 63;
  const int lm = lane & 15, lg = lane >> 4;
  const int wm = wave >> 1, wn = wave & 1;
  const int m0 = blockIdx.y * 128, n0 = blockIdx.x * TN;

  const int lrow = lane >> 3;                 // 0..7
  const int gseg = (lane & 7) ^ lrow;         // global col-seg (XOR swizzle)
  const size_t a_base = (size_t)(m0 + 32 * wave + lrow) * K + gseg * 8;
  u16* const a_lds = &As[(32 * wave) * 64];
  const size_t b_base = (size_t)(n0 + (TN / 4) * wave + lrow) * K + gseg * 8;
  u16* const b_lds = &Bs[((TN / 4) * wave) * 64];

  f32x4 acc[4][NT];
#pragma unroll
  for (int mt = 0; mt < 4; ++mt)
#pragma unroll
    for (int nt = 0; nt < NT; ++nt)
#pragma unroll
      for (int i = 0; i < 4; ++i) acc[mt][nt][i] = 0.f;

  for (int k0 = 0; k0 < K; k0 += 64) {
    __syncthreads();
#pragma unroll
    for (int i = 0; i < 4; ++i)
      gl_lds16(A + a_base + (size_t)(8 * i) * K + k0, a_lds + i * 8 * 64);
#pragma unroll
    for (int i = 0; i < NT; ++i)
      gl_lds16(BT + b_base + (size_t)(8 * i) * K + k0, b_lds + i * 8 * 64);
    __syncthreads();

#pragma unroll
    for (int h = 0; h < 2; ++h) {
      const int rs = ((lg + 4 * h) ^ (lm & 7)) * 8;
      bf16x8 af[4], bfr[NT];
#pragma unroll
      for (int mt = 0; mt < 4; ++mt)
        af[mt] = *(const bf16x8*)&As[(64 * wm + 16 * mt + lm) * 64 + rs];
#pragma unroll
      for (int nt = 0; nt < NT; ++nt)
        bfr[nt] = *(const bf16x8*)&Bs[((TN / 2) * wn + 16 * nt + lm) * 64 + rs];
#pragma unroll
      for (int mt = 0; mt < 4; ++mt)
#pragma unroll
        for (int nt = 0; nt < NT; ++nt)
          acc[mt][nt] = MFMA32(af[mt], bfr[nt], acc[mt][nt]);
    }
  }

#pragma unroll
  for (int nt = 0; nt < NT; ++nt) {
    int gc = n0 + (TN / 2) * wn + 16 * nt + lm;
    float bv = bias[gc];
    float sc = (gc < qcols) ? qscale : 1.f;
#pragma unroll
    for (int mt = 0; mt < 4; ++mt) {
#pragma unroll
      for (int i = 0; i < 4; ++i) {
        int gr = m0 + 64 * wm + 16 * mt + 4 * lg + i;
        float v = (acc[mt][nt][i] + bv) * sc;
        if (OUT_BF16)
          ((u16*)Cout)[(size_t)gr * N + gc] = f2bf(v);
        else
          ((float*)Cout)[(size_t)gr * N + gc] = v;
      }
    }
  }
}

// ---------------- flash attention, MFMA bf16, m=0 softmax, S^T ----------------
// 1D grid 1024: x = qtp*32+bh (XCD-affine); balanced qt = qtp<16?qtp:47-qtp.
// Wave w owns Q-rows [64qt+16w,+16). S^T = K*Q^T (A=K frags from LDS, B=Q
// frags in registers): lane (lg,lm) holds S^T[s=16c+4lg+r][q=16w+lm]. p =
// exp2(S^T) packed in-register as the A-frag of 16x16x16 MFMA (m=lm=q,
// k=4lg+r=s) -- P NEVER round-trips LDS. V B-frags: ds_read_b64 from Vt[d][s]
// (2-way bank alias, free). psum per-lane scalar (q=16w+lm), butterfly over
// lg (xor 16,32); inv redistributed via shfl lane 20*lg+r. 2-deep K/V
// register prefetch. Epilogue bounces O through Ks for 16B coalesced stores.
__global__ __launch_bounds__(256) void attn_kernel(const u16* __restrict__ qkv,
                                                   u16* __restrict__ yb) {
  __shared__ __align__(16) u16 Ks[64][72];
  __shared__ __align__(16) u16 Vt[64][72];

  const int t = threadIdx.x;
  const int wave = t >> 6, lane = t & 63;
  const int lm = lane & 15, lg = lane >> 4;
  const int kg8 = lg << 3;
  const int x = blockIdx.x;
  const int bh = x & 31, qtp = x >> 5;
  const int qt = (qtp < 16) ? qtp : 47 - qtp;  // CU-balanced map
  const int b = bh >> 4, h = bh & 15;
  const int q0 = qt * 64;
  const size_t rowstride = 3 * Cz;
  const u16* qbase = qkv + (size_t)b * Tz * rowstride + h * Dz;

  // Q fragments: B-operand of the S^T MFMA (lane lm = q-col, elems = d)
  bf16x8 qf[2];
  {
    const u16* qrow = qbase + (size_t)(q0 + wave * 16 + lm) * rowstride + kg8;
    qf[0] = *(const bf16x8*)qrow;
    qf[1] = *(const bf16x8*)(qrow + 32);
  }

  float psum = 0.f;  // l for q = 16*wave + lm (partial over this lane's s)
  f32x4 Oa[4];       // Oa[dt][r] = O[q=16w+4lg+r][d=16dt+lm]
#pragma unroll
  for (int i = 0; i < 4; ++i)
#pragma unroll
    for (int j = 0; j < 4; ++j) Oa[i][j] = 0.f;

  // staging offsets
  const int ksr = t >> 2, kds = (t & 3) << 4;   // K: row, 16-col seg
  const int vsp = t & 31, vds = (t >> 5) << 3;  // V: s-pair, 8-d seg
  const u16* kbase = qbase + Cz + (size_t)ksr * rowstride + kds;
  const u16* vbase = qbase + 2 * Cz + (size_t)(2 * vsp) * rowstride + vds;
  const size_t tilestep = 64 * rowstride;

  uint4 krA[2], vrA[2], krB[2], vrB[2];
  {  // prologue: prefetch tiles 0 and min(1,qt)
    krA[0] = *(const uint4*)kbase;
    krA[1] = *(const uint4*)(kbase + 8);
    vrA[0] = *(const uint4*)vbase;
    vrA[1] = *(const uint4*)(vbase + rowstride);
    const size_t t1 = (qt >= 1) ? tilestep : 0;
    krB[0] = *(const uint4*)(kbase + t1);
    krB[1] = *(const uint4*)(kbase + t1 + 8);
    vrB[0] = *(const uint4*)(vbase + t1);
    vrB[1] = *(const uint4*)(vbase + t1 + rowstride);
  }

  auto stage = [&](uint4 (&kr)[2], uint4 (&vr)[2], int ktc) {
    __syncthreads();  // prior stage's Ks/Vt reads complete
    *(uint4*)&Ks[ksr][kds] = kr[0];
    *(uint4*)&Ks[ksr][kds + 8] = kr[1];
    {
      unsigned av[4] = {vr[0].x, vr[0].y, vr[0].z, vr[0].w};
      unsigned cv[4] = {vr[1].x, vr[1].y, vr[1].z, vr[1].w};
#pragma unroll
      for (int j = 0; j < 4; ++j) {
        unsigned w0 = (av[j] & 0xffffu) | (cv[j] << 16);
        unsigned w1 = (av[j] >> 16) | (cv[j] & 0xffff0000u);
        *(unsigned*)&Vt[vds + 2 * j][2 * vsp] = w0;
        *(unsigned*)&Vt[vds + 2 * j + 1][2 * vsp] = w1;
      }
    }
    __syncthreads();

    // prefetch tile ktc+2 into this stage's regs (overlaps compute)
    if (ktc + 2 <= qt) {
      const u16* kp = kbase + (size_t)(ktc + 2) * tilestep;
      const u16* vp = vbase + (size_t)(ktc + 2) * tilestep;
      kr[0] = *(const uint4*)kp;
      kr[1] = *(const uint4*)(kp + 8);
      vr[0] = *(const uint4*)vp;
      vr[1] = *(const uint4*)(vp + rowstride);
    }

    // ---- S^T = K Q^T (pre-scaled): lane gets s=16c+4lg+r, q=16w+lm ----
    f32x4 S[4];
#pragma unroll
    for (int c = 0; c < 4; ++c) {
      bf16x8 k0 = *(const bf16x8*)&Ks[c * 16 + lm][kg8];
      bf16x8 k1 = *(const bf16x8*)&Ks[c * 16 + lm][32 + kg8];
      f32x4 s;
#pragma unroll
      for (int i = 0; i < 4; ++i) s[i] = 0.f;
      s = MFMA32(k0, qf[0], s);
      s = MFMA32(k1, qf[1], s);
      S[c] = s;
    }

    // ---- p = exp2(S^T), diag mask, accumulate l, pack A-frags in-reg ----
    const bool diag = (ktc == qt);
    const int qloc = 16 * wave + lm;
    bf16x4 pf[4];
#pragma unroll
    for (int c = 0; c < 4; ++c) {
#pragma unroll
      for (int r = 0; r < 4; ++r) {
        float p = fexp2(S[c][r]);
        if (diag && (c * 16 + 4 * lg + r) > qloc) p = 0.f;
        psum += p;
        pf[c][r] = (short)f2bf(p);
      }
    }

    // ---- O += P V: K=16 MFMAs, A=pf (registers), B from Vt[d][s] ----
#pragma unroll
    for (int dt = 0; dt < 4; ++dt) {
#pragma unroll
      for (int c = 0; c < 4; ++c) {
        bf16x4 vfr = *(const bf16x4*)&Vt[16 * dt + lm][c * 16 + 4 * lg];
        Oa[dt] = mfma16(pf[c], vfr, Oa[dt]);
      }
    }
  };

  for (int kt = 0; kt <= qt; kt += 2) {
    stage(krA, vrA, kt);
    if (kt + 1 <= qt) stage(krB, vrB, kt + 1);
  }

  // ---- epilogue: l-reduce over lg, redistribute inv, bounce via Ks ----
  float s = psum;
  s += __shfl_xor(s, 16);
  s += __shfl_xor(s, 32);
  const float linv = 1.f / s;  // l(q=16w+lm), valid at all lg
  float invq[4];
#pragma unroll
  for (int r = 0; r < 4; ++r)
    invq[r] = __shfl(linv, 20 * lg + r);  // lane with lm = 4lg+r (same lg)
  __syncthreads();  // all Ks/Vt readers done; reuse Ks as store bounce
#pragma unroll
  for (int dt = 0; dt < 4; ++dt)
#pragma unroll
    for (int r = 0; r < 4; ++r)
      Ks[16 * wave + 4 * lg + r][16 * dt + lm] = f2bf(Oa[dt][r] * invq[r]);
  __syncthreads();
  {
    const int row = lane >> 2, seg = lane & 3;
    const uint4* src = (const uint4*)&Ks[16 * wave + row][seg * 16];
    uint4 v0 = src[0];
    uint4 v1 = src[1];
    u16* dst = yb + (size_t)(b * Tz + q0 + 16 * wave + row) * Cz + h * Dz + seg * 16;
    *(uint4*)dst = v0;
    *(uint4*)(dst + 8) = v1;
  }
}

extern "C" void kernel_launch(void* const* d_in, const int* in_sizes, int n_in,
                              void* d_out, int out_size, void* d_ws, size_t ws_size,
                              hipStream_t stream) {
  const float* x      = (const float*)d_in[0];
  const float* w_attn = (const float*)d_in[1];
  const float* b_attn = (const float*)d_in[2];
  const float* w_proj = (const float*)d_in[3];
  const float* b_proj = (const float*)d_in[4];

  char* ws = (char*)d_ws;
  u16* xb   = (u16*)(ws);                        //  8 MB: x bf16 [4096,1024]
  u16* waT  = (u16*)(ws + (8ull << 20));         //  6 MB: w_attn^T bf16 [3072,1024]
  u16* wpT  = (u16*)(ws + (14ull << 20));        //  2 MB: w_proj^T bf16 [1024,1024]
  u16* qkvb = (u16*)(ws + (16ull << 20));        // 24 MB: qkv bf16 (q pre-scaled)
  u16* yb   = (u16*)(ws + (40ull << 20));        //  8 MB: y bf16 [4096,1024]

  const int M = Bz * Tz;  // 4096

  prep_kernel<<<NCAST + NTA + 1024, 256, 0, stream>>>(x, w_attn, w_proj, xb, waT, wpT);
  gemm_bt<true, 128><<<dim3(3 * Cz / 128, M / 128), 256, 0, stream>>>(
      xb, waT, b_attn, qkvb, M, 3 * Cz, Cz, Cz, QSCALE);
  attn_kernel<<<1024, 256, 0, stream>>>(qkvb, yb);
  gemm_bt<false, 64><<<dim3(Cz / 64, M / 128), 256, 0, stream>>>(
      yb, wpT, b_proj, d_out, M, Cz, Cz, 0, 1.f);
}

// Round 11
// 203.590 us; speedup vs baseline: 1.0443x; 1.0211x over previous
//
#include <hip/hip_runtime.h>

// Causal self-attention fwd: B=2,T=2048,C=1024,H=16,D=64, scale=0.1/sqrt(D)
// prep (cast x + transpose weights); qkv GEMM 128x128 BK=64 w/ global_load_lds
// + XOR seg swizzle, q pre-scaled by SCALE*log2e; flash attn (S^T = K*Q^T, P
// in registers as 16x16x16-MFMA A-frags; m=0 softmax; double-buffered K/V LDS
// with conflict-free strides, 1 barrier/stage; XCD-affine CU-balanced grid);
// proj GEMM.

#define Bz 2
#define Tz 2048
#define Cz 1024
#define Hz 16
#define Dz 64
// SCALE * log2(e): q pre-scaled so attn does p = exp2(S) directly
#define QSCALE 0.01803368801111437f
// LDS row strides (u16): chosen so frag reads hit <=2 lanes/bank (free):
//   Ks 76 -> 38 dw: b128 read bank = (6lm+4lg)%32, 2-way max
//   Vt 74 -> 37 dw: b64  read bank = (5lm+2lg)%32, 2-way max
#define KSS 76
#define VTS 74

typedef unsigned short u16;
typedef short bf16x4 __attribute__((ext_vector_type(4)));
typedef short bf16x8 __attribute__((ext_vector_type(8)));
typedef float f32x4 __attribute__((ext_vector_type(4)));

#define MFMA32(A, B, C) __builtin_amdgcn_mfma_f32_16x16x32_bf16(A, B, C, 0, 0, 0)

// K=16 bf16 MFMA. Guard with __HIP_DEVICE_COMPILE__ (R8 lesson: __has_builtin
// is unreliable for aux-target builtins in the host pass).
__device__ inline f32x4 mfma16(bf16x4 a, bf16x4 b, f32x4 c) {
#if defined(__HIP_DEVICE_COMPILE__)
  return __builtin_amdgcn_mfma_f32_16x16x16bf16_1k(a, b, c, 0, 0, 0);
#else
  return c;  // host pass placeholder, never executed
#endif
}

__device__ inline u16 f2bf(float f) {  // round-half-up: 2 VALU, <=0.5 ulp
  return (u16)((__float_as_uint(f) + 0x8000u) >> 16);
}

__device__ inline float fexp2(float x) {  // raw v_exp_f32 (R6-proven guard)
#if __has_builtin(__builtin_amdgcn_exp2f)
  return __builtin_amdgcn_exp2f(x);
#else
  return exp2f(x);
#endif
}

__device__ inline void gl_lds16(const u16* g, u16* l) {
  __builtin_amdgcn_global_load_lds(
      (const __attribute__((address_space(1))) void*)g,
      (__attribute__((address_space(3))) void*)l, 16, 0, 0);
}

// ------------- prep: cast x->bf16 + transpose/cast both weights -------------
#define NCAST 4096   // (4096*1024/4)/256
#define NTA   3072   // (3072/32)*(1024/32)
__global__ __launch_bounds__(256) void prep_kernel(const float* __restrict__ x,
                                                   const float* __restrict__ wa,
                                                   const float* __restrict__ wp,
                                                   u16* __restrict__ xb,
                                                   u16* __restrict__ waT,
                                                   u16* __restrict__ wpT) {
  const int bx = blockIdx.x, t = threadIdx.x;
  if (bx < NCAST) {
    int i = bx * 256 + t;
    float4 v = ((const float4*)x)[i];
    ushort4 o = {f2bf(v.x), f2bf(v.y), f2bf(v.z), f2bf(v.w)};
    ((ushort4*)xb)[i] = o;
    return;
  }
  __shared__ float tile[32][33];
  const float* W;
  u16* WT;
  int N, idx;
  if (bx < NCAST + NTA) {
    W = wa; WT = waT; N = 3 * Cz; idx = bx - NCAST;
  } else {
    W = wp; WT = wpT; N = Cz; idx = bx - NCAST - NTA;
  }
  const int n0 = (idx % (N / 32)) * 32, k0 = (idx / (N / 32)) * 32;
  const int tx = t & 31, ty = t >> 5;  // (32, 8)
#pragma unroll
  for (int i = 0; i < 4; ++i)
    tile[ty + 8 * i][tx] = W[(size_t)(k0 + ty + 8 * i) * N + n0 + tx];
  __syncthreads();
#pragma unroll
  for (int i = 0; i < 4; ++i)
    WT[(size_t)(n0 + ty + 8 * i) * Cz + k0 + tx] = f2bf(tile[tx][ty + 8 * i]);
}

// ---------- C[M][N] = A[M][K]*BT[N][K]^T + bias; 128xTN tile, BK=64 ----------
template <bool OUT_BF16, int TN>
__global__ __launch_bounds__(256) void gemm_bt(const u16* __restrict__ A,
                                               const u16* __restrict__ BT,
                                               const float* __restrict__ bias,
                                               void* __restrict__ Cout,
                                               int M, int N, int K,
                                               int qcols, float qscale) {
  __shared__ __align__(16) u16 As[128 * 64];
  __shared__ __align__(16) u16 Bs[TN * 64];
  constexpr int NT = TN / 32;
  const int t = threadIdx.x;
  const int wave = t >> 6, lane = t & 63;
  const int lm = lane & 15, lg = lane >> 4;
  const int wm = wave >> 1, wn = wave & 1;
  const int m0 = blockIdx.y * 128, n0 = blockIdx.x * TN;

  const int lrow = lane >> 3;                 // 0..7
  const int gseg = (lane & 7) ^ lrow;         // global col-seg (XOR swizzle)
  const size_t a_base = (size_t)(m0 + 32 * wave + lrow) * K + gseg * 8;
  u16* const a_lds = &As[(32 * wave) * 64];
  const size_t b_base = (size_t)(n0 + (TN / 4) * wave + lrow) * K + gseg * 8;
  u16* const b_lds = &Bs[((TN / 4) * wave) * 64];

  f32x4 acc[4][NT];
#pragma unroll
  for (int mt = 0; mt < 4; ++mt)
#pragma unroll
    for (int nt = 0; nt < NT; ++nt)
#pragma unroll
      for (int i = 0; i < 4; ++i) acc[mt][nt][i] = 0.f;

  for (int k0 = 0; k0 < K; k0 += 64) {
    __syncthreads();
#pragma unroll
    for (int i = 0; i < 4; ++i)
      gl_lds16(A + a_base + (size_t)(8 * i) * K + k0, a_lds + i * 8 * 64);
#pragma unroll
    for (int i = 0; i < NT; ++i)
      gl_lds16(BT + b_base + (size_t)(8 * i) * K + k0, b_lds + i * 8 * 64);
    __syncthreads();

#pragma unroll
    for (int h = 0; h < 2; ++h) {
      const int rs = ((lg + 4 * h) ^ (lm & 7)) * 8;
      bf16x8 af[4], bfr[NT];
#pragma unroll
      for (int mt = 0; mt < 4; ++mt)
        af[mt] = *(const bf16x8*)&As[(64 * wm + 16 * mt + lm) * 64 + rs];
#pragma unroll
      for (int nt = 0; nt < NT; ++nt)
        bfr[nt] = *(const bf16x8*)&Bs[((TN / 2) * wn + 16 * nt + lm) * 64 + rs];
#pragma unroll
      for (int mt = 0; mt < 4; ++mt)
#pragma unroll
        for (int nt = 0; nt < NT; ++nt)
          acc[mt][nt] = MFMA32(af[mt], bfr[nt], acc[mt][nt]);
    }
  }

#pragma unroll
  for (int nt = 0; nt < NT; ++nt) {
    int gc = n0 + (TN / 2) * wn + 16 * nt + lm;
    float bv = bias[gc];
    float sc = (gc < qcols) ? qscale : 1.f;
#pragma unroll
    for (int mt = 0; mt < 4; ++mt) {
#pragma unroll
      for (int i = 0; i < 4; ++i) {
        int gr = m0 + 64 * wm + 16 * mt + 4 * lg + i;
        float v = (acc[mt][nt][i] + bv) * sc;
        if (OUT_BF16)
          ((u16*)Cout)[(size_t)gr * N + gc] = f2bf(v);
        else
          ((float*)Cout)[(size_t)gr * N + gc] = v;
      }
    }
  }
}

// ---------------- flash attention, MFMA bf16, m=0 softmax, S^T ----------------
// 1D grid 1024: x = qtp*32+bh (XCD-affine); balanced qt = qtp<16?qtp:47-qtp.
// Wave w owns Q-rows [64qt+16w,+16). S^T = K*Q^T: lane (lg,lm) holds
// S^T[s=16c+4lg+r][q=16w+lm]; p = exp2(S^T) packed in-register as the A-frag
// of 16x16x16 MFMA -- P never touches LDS. Double-buffered Ks/Vt with
// conflict-free strides (KSS/VTS): ONE barrier per stage; write of tile kt+1
// overlaps compute of kt; global loads issued 2 stages ahead. psum per-lane
// scalar, butterfly xor 16/32; inv redistributed via shfl lane 20lg+r.
// Epilogue bounces O through Ks[0] for 16B coalesced stores.
__global__ __launch_bounds__(256) void attn_kernel(const u16* __restrict__ qkv,
                                                   u16* __restrict__ yb) {
  __shared__ __align__(16) u16 Ks[2][64][KSS];
  __shared__ __align__(16) u16 Vt[2][64][VTS];

  const int t = threadIdx.x;
  const int wave = t >> 6, lane = t & 63;
  const int lm = lane & 15, lg = lane >> 4;
  const int kg8 = lg << 3;
  const int x = blockIdx.x;
  const int bh = x & 31, qtp = x >> 5;
  const int qt = (qtp < 16) ? qtp : 47 - qtp;  // CU-balanced map
  const int b = bh >> 4, h = bh & 15;
  const int q0 = qt * 64;
  const size_t rowstride = 3 * Cz;
  const u16* qbase = qkv + (size_t)b * Tz * rowstride + h * Dz;

  // Q fragments: B-operand of the S^T MFMA (lane lm = q-col, elems = d)
  bf16x8 qf[2];
  {
    const u16* qrow = qbase + (size_t)(q0 + wave * 16 + lm) * rowstride + kg8;
    qf[0] = *(const bf16x8*)qrow;
    qf[1] = *(const bf16x8*)(qrow + 32);
  }

  float psum = 0.f;  // l for q = 16*wave + lm (partial over this lane's s)
  f32x4 Oa[4];       // Oa[dt][r] = O[q=16w+4lg+r][d=16dt+lm]
#pragma unroll
  for (int i = 0; i < 4; ++i)
#pragma unroll
    for (int j = 0; j < 4; ++j) Oa[i][j] = 0.f;

  // staging offsets
  const int ksr = t >> 2, kds = (t & 3) << 4;   // K: row, 16-col seg
  const int vsp = t & 31, vds = (t >> 5) << 3;  // V: s-pair, 8-d seg
  const u16* kbase = qbase + Cz + (size_t)ksr * rowstride + kds;
  const u16* vbase = qbase + 2 * Cz + (size_t)(2 * vsp) * rowstride + vds;
  const size_t tilestep = 64 * rowstride;

  uint4 kr[2], vr[2];
  auto load_tile = [&](int kt) {
    const u16* kp = kbase + (size_t)kt * tilestep;
    const u16* vp = vbase + (size_t)kt * tilestep;
    kr[0] = *(const uint4*)kp;
    kr[1] = *(const uint4*)(kp + 8);
    vr[0] = *(const uint4*)vp;
    vr[1] = *(const uint4*)(vp + rowstride);
  };
  auto stage_write = [&](int buf) {
    *(uint4*)&Ks[buf][ksr][kds] = kr[0];
    *(uint4*)&Ks[buf][ksr][kds + 8] = kr[1];
    unsigned av[4] = {vr[0].x, vr[0].y, vr[0].z, vr[0].w};
    unsigned cv[4] = {vr[1].x, vr[1].y, vr[1].z, vr[1].w};
#pragma unroll
    for (int j = 0; j < 4; ++j) {
      unsigned w0 = (av[j] & 0xffffu) | (cv[j] << 16);
      unsigned w1 = (av[j] >> 16) | (cv[j] & 0xffff0000u);
      *(unsigned*)&Vt[buf][vds + 2 * j][2 * vsp] = w0;
      *(unsigned*)&Vt[buf][vds + 2 * j + 1][2 * vsp] = w1;
    }
  };

  // prologue: tile 0 staged to buf0; tile 1 pending in regs
  load_tile(0);
  stage_write(0);
  load_tile(1);  // tile 1 always exists in memory (qkv has 32 tiles/b)

  for (int kt = 0; kt <= qt; ++kt) {
    __syncthreads();  // buf(kt&1) visible; prior readers of buf(1-(kt&1)) done
    const int cb = kt & 1;
    if (kt + 1 <= qt) {
      stage_write(1 - cb);
      if (kt + 2 <= qt) load_tile(kt + 2);
    }

    // ---- S^T = K Q^T (pre-scaled): lane gets s=16c+4lg+r, q=16w+lm ----
    f32x4 S[4];
#pragma unroll
    for (int c = 0; c < 4; ++c) {
      bf16x8 k0 = *(const bf16x8*)&Ks[cb][c * 16 + lm][kg8];
      bf16x8 k1 = *(const bf16x8*)&Ks[cb][c * 16 + lm][32 + kg8];
      f32x4 s;
#pragma unroll
      for (int i = 0; i < 4; ++i) s[i] = 0.f;
      s = MFMA32(k0, qf[0], s);
      s = MFMA32(k1, qf[1], s);
      S[c] = s;
    }

    // ---- p = exp2(S^T), diag mask, accumulate l, pack A-frags in-reg ----
    const bool diag = (kt == qt);
    const int qloc = 16 * wave + lm;
    bf16x4 pf[4];
#pragma unroll
    for (int c = 0; c < 4; ++c) {
#pragma unroll
      for (int r = 0; r < 4; ++r) {
        float p = fexp2(S[c][r]);
        if (diag && (c * 16 + 4 * lg + r) > qloc) p = 0.f;
        psum += p;
        pf[c][r] = (short)f2bf(p);
      }
    }

    // ---- O += P V: K=16 MFMAs, A=pf (registers), B from Vt[d][s] ----
#pragma unroll
    for (int dt = 0; dt < 4; ++dt) {
#pragma unroll
      for (int c = 0; c < 4; ++c) {
        bf16x4 vfr = *(const bf16x4*)&Vt[cb][16 * dt + lm][c * 16 + 4 * lg];
        Oa[dt] = mfma16(pf[c], vfr, Oa[dt]);
      }
    }
  }

  // ---- epilogue: l-reduce over lg, redistribute inv, bounce via Ks[0] ----
  float s = psum;
  s += __shfl_xor(s, 16);
  s += __shfl_xor(s, 32);
  const float linv = 1.f / s;  // l(q=16w+lm), valid at all lg
  float invq[4];
#pragma unroll
  for (int r = 0; r < 4; ++r)
    invq[r] = __shfl(linv, 20 * lg + r);  // lane with lm = 4lg+r (same lg)
  __syncthreads();  // all Ks/Vt readers done; reuse Ks[0] as store bounce
#pragma unroll
  for (int dt = 0; dt < 4; ++dt)
#pragma unroll
    for (int r = 0; r < 4; ++r)
      Ks[0][16 * wave + 4 * lg + r][16 * dt + lm] = f2bf(Oa[dt][r] * invq[r]);
  __syncthreads();
  {
    const int row = lane >> 2, seg = lane & 3;
    const uint4* src = (const uint4*)&Ks[0][16 * wave + row][seg * 16];
    uint4 v0 = src[0];
    uint4 v1 = src[1];
    u16* dst = yb + (size_t)(b * Tz + q0 + 16 * wave + row) * Cz + h * Dz + seg * 16;
    *(uint4*)dst = v0;
    *(uint4*)(dst + 8) = v1;
  }
}

extern "C" void kernel_launch(void* const* d_in, const int* in_sizes, int n_in,
                              void* d_out, int out_size, void* d_ws, size_t ws_size,
                              hipStream_t stream) {
  const float* x      = (const float*)d_in[0];
  const float* w_attn = (const float*)d_in[1];
  const float* b_attn = (const float*)d_in[2];
  const float* w_proj = (const float*)d_in[3];
  const float* b_proj = (const float*)d_in[4];

  char* ws = (char*)d_ws;
  u16* xb   = (u16*)(ws);                        //  8 MB: x bf16 [4096,1024]
  u16* waT  = (u16*)(ws + (8ull << 20));         //  6 MB: w_attn^T bf16 [3072,1024]
  u16* wpT  = (u16*)(ws + (14ull << 20));        //  2 MB: w_proj^T bf16 [1024,1024]
  u16* qkvb = (u16*)(ws + (16ull << 20));        // 24 MB: qkv bf16 (q pre-scaled)
  u16* yb   = (u16*)(ws + (40ull << 20));        //  8 MB: y bf16 [4096,1024]

  const int M = Bz * Tz;  // 4096

  prep_kernel<<<NCAST + NTA + 1024, 256, 0, stream>>>(x, w_attn, w_proj, xb, waT, wpT);
  gemm_bt<true, 128><<<dim3(3 * Cz / 128, M / 128), 256, 0, stream>>>(
      xb, waT, b_attn, qkvb, M, 3 * Cz, Cz, Cz, QSCALE);
  attn_kernel<<<1024, 256, 0, stream>>>(qkvb, yb);
  gemm_bt<false, 64><<<dim3(Cz / 64, M / 128), 256, 0, stream>>>(
      yb, wpT, b_proj, d_out, M, Cz, Cz, 0, 1.f);
}

// Round 12
// 171.450 us; speedup vs baseline: 1.2400x; 1.1875x over previous
//
#include <hip/hip_runtime.h>

// Causal self-attention fwd: B=2,T=2048,C=1024,H=16,D=64, scale=0.1/sqrt(D)
// prep (cast x + transpose weights); qkv GEMM 128x128 BK=64 (global_load_lds,
// XOR seg swizzle, q pre-scaled by SCALE*log2e, V written PRE-TRANSPOSED to
// vT[d][s]); flash attn (S^T = K*Q^T, P in registers as 16x16x16-MFMA
// A-frags; K AND V staged via global_load_lds w/ global-side XOR swizzle --
// zero DS-write staging; double-buffered, 1 barrier/stage; m=0 softmax;
// XCD-affine CU-balanced grid); proj GEMM.

#define Bz 2
#define Tz 2048
#define Cz 1024
#define Hz 16
#define Dz 64
// SCALE * log2(e): q pre-scaled so attn does p = exp2(S) directly
#define QSCALE 0.01803368801111437f

typedef unsigned short u16;
typedef short bf16x4 __attribute__((ext_vector_type(4)));
typedef short bf16x8 __attribute__((ext_vector_type(8)));
typedef float f32x4 __attribute__((ext_vector_type(4)));

#define MFMA32(A, B, C) __builtin_amdgcn_mfma_f32_16x16x32_bf16(A, B, C, 0, 0, 0)

// K=16 bf16 MFMA. Guard with __HIP_DEVICE_COMPILE__ (R8 lesson: __has_builtin
// is unreliable for aux-target builtins in the host pass).
__device__ inline f32x4 mfma16(bf16x4 a, bf16x4 b, f32x4 c) {
#if defined(__HIP_DEVICE_COMPILE__)
  return __builtin_amdgcn_mfma_f32_16x16x16bf16_1k(a, b, c, 0, 0, 0);
#else
  return c;  // host pass placeholder, never executed
#endif
}

__device__ inline u16 f2bf(float f) {  // round-half-up: 2 VALU, <=0.5 ulp
  return (u16)((__float_as_uint(f) + 0x8000u) >> 16);
}

__device__ inline float fexp2(float x) {  // raw v_exp_f32 (R6-proven guard)
#if __has_builtin(__builtin_amdgcn_exp2f)
  return __builtin_amdgcn_exp2f(x);
#else
  return exp2f(x);
#endif
}

__device__ inline void gl_lds16(const u16* g, u16* l) {
  __builtin_amdgcn_global_load_lds(
      (const __attribute__((address_space(1))) void*)g,
      (__attribute__((address_space(3))) void*)l, 16, 0, 0);
}

// ------------- prep: cast x->bf16 + transpose/cast both weights -------------
#define NCAST 4096   // (4096*1024/4)/256
#define NTA   3072   // (3072/32)*(1024/32)
__global__ __launch_bounds__(256) void prep_kernel(const float* __restrict__ x,
                                                   const float* __restrict__ wa,
                                                   const float* __restrict__ wp,
                                                   u16* __restrict__ xb,
                                                   u16* __restrict__ waT,
                                                   u16* __restrict__ wpT) {
  const int bx = blockIdx.x, t = threadIdx.x;
  if (bx < NCAST) {
    int i = bx * 256 + t;
    float4 v = ((const float4*)x)[i];
    ushort4 o = {f2bf(v.x), f2bf(v.y), f2bf(v.z), f2bf(v.w)};
    ((ushort4*)xb)[i] = o;
    return;
  }
  __shared__ float tile[32][33];
  const float* W;
  u16* WT;
  int N, idx;
  if (bx < NCAST + NTA) {
    W = wa; WT = waT; N = 3 * Cz; idx = bx - NCAST;
  } else {
    W = wp; WT = wpT; N = Cz; idx = bx - NCAST - NTA;
  }
  const int n0 = (idx % (N / 32)) * 32, k0 = (idx / (N / 32)) * 32;
  const int tx = t & 31, ty = t >> 5;  // (32, 8)
#pragma unroll
  for (int i = 0; i < 4; ++i)
    tile[ty + 8 * i][tx] = W[(size_t)(k0 + ty + 8 * i) * N + n0 + tx];
  __syncthreads();
#pragma unroll
  for (int i = 0; i < 4; ++i)
    WT[(size_t)(n0 + ty + 8 * i) * Cz + k0 + tx] = f2bf(tile[tx][ty + 8 * i]);
}

// ---------- C[M][N] = A[M][K]*BT[N][K]^T + bias; 128xTN tile, BK=64 ----------
// VSPLIT: cols >= 2C are V -- written transposed to vTout[(b*1024 + (gc-2C))]
// [s] as ushort4 (lane's 4 consecutive s), skipping Cout.
template <bool OUT_BF16, int TN, bool VSPLIT>
__global__ __launch_bounds__(256) void gemm_bt(const u16* __restrict__ A,
                                               const u16* __restrict__ BT,
                                               const float* __restrict__ bias,
                                               void* __restrict__ Cout,
                                               u16* __restrict__ vTout,
                                               int M, int N, int K,
                                               int qcols, float qscale) {
  __shared__ __align__(16) u16 As[128 * 64];
  __shared__ __align__(16) u16 Bs[TN * 64];
  constexpr int NT = TN / 32;
  const int t = threadIdx.x;
  const int wave = t >> 6, lane = t & 63;
  const int lm = lane & 15, lg = lane >> 4;
  const int wm = wave >> 1, wn = wave & 1;
  const int m0 = blockIdx.y * 128, n0 = blockIdx.x * TN;

  const int lrow = lane >> 3;                 // 0..7
  const int gseg = (lane & 7) ^ lrow;         // global col-seg (XOR swizzle)
  const size_t a_base = (size_t)(m0 + 32 * wave + lrow) * K + gseg * 8;
  u16* const a_lds = &As[(32 * wave) * 64];
  const size_t b_base = (size_t)(n0 + (TN / 4) * wave + lrow) * K + gseg * 8;
  u16* const b_lds = &Bs[((TN / 4) * wave) * 64];

  f32x4 acc[4][NT];
#pragma unroll
  for (int mt = 0; mt < 4; ++mt)
#pragma unroll
    for (int nt = 0; nt < NT; ++nt)
#pragma unroll
      for (int i = 0; i < 4; ++i) acc[mt][nt][i] = 0.f;

  for (int k0 = 0; k0 < K; k0 += 64) {
    __syncthreads();
#pragma unroll
    for (int i = 0; i < 4; ++i)
      gl_lds16(A + a_base + (size_t)(8 * i) * K + k0, a_lds + i * 8 * 64);
#pragma unroll
    for (int i = 0; i < NT; ++i)
      gl_lds16(BT + b_base + (size_t)(8 * i) * K + k0, b_lds + i * 8 * 64);
    __syncthreads();

#pragma unroll
    for (int h = 0; h < 2; ++h) {
      const int rs = ((lg + 4 * h) ^ (lm & 7)) * 8;
      bf16x8 af[4], bfr[NT];
#pragma unroll
      for (int mt = 0; mt < 4; ++mt)
        af[mt] = *(const bf16x8*)&As[(64 * wm + 16 * mt + lm) * 64 + rs];
#pragma unroll
      for (int nt = 0; nt < NT; ++nt)
        bfr[nt] = *(const bf16x8*)&Bs[((TN / 2) * wn + 16 * nt + lm) * 64 + rs];
#pragma unroll
      for (int mt = 0; mt < 4; ++mt)
#pragma unroll
        for (int nt = 0; nt < NT; ++nt)
          acc[mt][nt] = MFMA32(af[mt], bfr[nt], acc[mt][nt]);
    }
  }

#pragma unroll
  for (int nt = 0; nt < NT; ++nt) {
    int gc = n0 + (TN / 2) * wn + 16 * nt + lm;
    float bv = bias[gc];
    if (VSPLIT && gc >= 2 * Cz) {
      // V column -> transposed store: vTout[(b*1024 + dg)][s0..s0+3]
      const int dg = gc - 2 * Cz;
#pragma unroll
      for (int mt = 0; mt < 4; ++mt) {
        const int gr0 = m0 + 64 * wm + 16 * mt + 4 * lg;
        const int bb = gr0 >> 11, s0 = gr0 & 2047;
        ushort4 o = {f2bf(acc[mt][nt][0] + bv), f2bf(acc[mt][nt][1] + bv),
                     f2bf(acc[mt][nt][2] + bv), f2bf(acc[mt][nt][3] + bv)};
        *(ushort4*)(vTout + (((size_t)(bb * 1024 + dg)) << 11) + s0) = o;
      }
      continue;
    }
    float sc = (gc < qcols) ? qscale : 1.f;
#pragma unroll
    for (int mt = 0; mt < 4; ++mt) {
#pragma unroll
      for (int i = 0; i < 4; ++i) {
        int gr = m0 + 64 * wm + 16 * mt + 4 * lg + i;
        float v = (acc[mt][nt][i] + bv) * sc;
        if (OUT_BF16)
          ((u16*)Cout)[(size_t)gr * N + gc] = f2bf(v);
        else
          ((float*)Cout)[(size_t)gr * N + gc] = v;
      }
    }
  }
}

// ---------------- flash attention, MFMA bf16, m=0 softmax, S^T ----------------
// 1D grid 1024: x = qtp*32+bh (XCD-affine); balanced qt = qtp<16?qtp:47-qtp.
// Wave w owns Q-rows [64qt+16w,+16). S^T = K*Q^T; p = exp2(S^T) packed
// in-register as 16x16x16-MFMA A-frag (P never touches LDS). K and V staged
// with global_load_lds (w=16) into unpadded stride-64 LDS; conflicts killed
// by XOR swizzle on the GLOBAL address (seg_g = seg_l ^ (row&7)) -- legal
// since gl_lds global addrs are per-lane, LDS base wave-uniform (m104).
// Frag reads un-swizzle; K b128 and V b64 patterns are bank-minimal (free).
// Double-buffered, ONE barrier/stage; gl_lds for kt+1 issued right after the
// barrier. V comes from pre-transposed vT[d][s] (written by qkv GEMM).
__global__ __launch_bounds__(256) void attn_kernel(const u16* __restrict__ qkv,
                                                   const u16* __restrict__ vT,
                                                   u16* __restrict__ yb) {
  __shared__ __align__(16) u16 KsL[2][64 * 64];
  __shared__ __align__(16) u16 VtL[2][64 * 64];

  const int t = threadIdx.x;
  const int wave = t >> 6, lane = t & 63;
  const int lm = lane & 15, lg = lane >> 4;
  const int x = blockIdx.x;
  const int bh = x & 31, qtp = x >> 5;
  const int qt = (qtp < 16) ? qtp : 47 - qtp;  // CU-balanced map
  const int b = bh >> 4, h = bh & 15;
  const int q0 = qt * 64;
  const size_t rowstride = 3 * Cz;
  const u16* qbase = qkv + (size_t)b * Tz * rowstride + h * Dz;
  const u16* vTbh = vT + ((size_t)(b * Hz + h) * Dz) * Tz;  // [64][2048]

  // Q fragments: B-operand of the S^T MFMA (lane lm = q-col, elems = d)
  bf16x8 qf[2];
  {
    const u16* qrow = qbase + (size_t)(q0 + wave * 16 + lm) * rowstride + (lg << 3);
    qf[0] = *(const bf16x8*)qrow;
    qf[1] = *(const bf16x8*)(qrow + 32);
  }

  float psum = 0.f;  // l for q = 16*wave + lm (partial over this lane's s)
  f32x4 Oa[4];       // Oa[dt][r] = O[q=16w+4lg+r][d=16dt+lm]
#pragma unroll
  for (int i = 0; i < 4; ++i)
#pragma unroll
    for (int j = 0; j < 4; ++j) Oa[i][j] = 0.f;

  // staging: wave w stages rows [16w,16w+16) of both K and V tiles.
  // lane i -> row +(i>>3), LDS seg i&7 holding GLOBAL seg (i&7)^(i>>3).
  const int srow = lane >> 3;              // 0..7
  const int sgl = ((lane & 7) ^ srow) * 8; // global col offset (swizzled)
  const u16* kstg = qbase + Cz + (size_t)(16 * wave + srow) * rowstride + sgl;
  const u16* vstg = vTbh + (size_t)(16 * wave + srow) * Tz + sgl;

  auto stage_issue = [&](int kt, int buf) {
#pragma unroll
    for (int c2 = 0; c2 < 2; ++c2) {
      gl_lds16(kstg + (size_t)(8 * c2) * rowstride + (size_t)(64 * kt) * rowstride,
               &KsL[buf][(16 * wave + 8 * c2) * 64]);
      gl_lds16(vstg + (size_t)(8 * c2) * Tz + 64 * kt,
               &VtL[buf][(16 * wave + 8 * c2) * 64]);
    }
  };

  stage_issue(0, 0);  // prologue; first barrier drains it

  for (int kt = 0; kt <= qt; ++kt) {
    __syncthreads();  // buf(kt&1) loads drained; prior readers of other buf done
    const int cb = kt & 1;
    if (kt + 1 <= qt) stage_issue(kt + 1, 1 - cb);

    // ---- S^T = K Q^T (pre-scaled): lane gets s=16c+4lg+r, q=16w+lm ----
    f32x4 S[4];
#pragma unroll
    for (int c = 0; c < 4; ++c) {
      const int rb = (16 * c + lm) * 64;
      bf16x8 k0 = *(const bf16x8*)&KsL[cb][rb + ((lg ^ (lm & 7)) << 3)];
      bf16x8 k1 = *(const bf16x8*)&KsL[cb][rb + (((lg + 4) ^ (lm & 7)) << 3)];
      f32x4 s;
#pragma unroll
      for (int i = 0; i < 4; ++i) s[i] = 0.f;
      s = MFMA32(k0, qf[0], s);
      s = MFMA32(k1, qf[1], s);
      S[c] = s;
    }

    // ---- p = exp2(S^T), diag mask, accumulate l, pack A-frags in-reg ----
    const bool diag = (kt == qt);
    const int qloc = 16 * wave + lm;
    bf16x4 pf[4];
#pragma unroll
    for (int c = 0; c < 4; ++c) {
#pragma unroll
      for (int r = 0; r < 4; ++r) {
        float p = fexp2(S[c][r]);
        if (diag && (c * 16 + 4 * lg + r) > qloc) p = 0.f;
        psum += p;
        pf[c][r] = (short)f2bf(p);
      }
    }

    // ---- O += P V: K=16 MFMAs, A=pf (registers), B from VtL[d][s] ----
#pragma unroll
    for (int dt = 0; dt < 4; ++dt) {
      const int rb = (16 * dt + lm) * 64;
#pragma unroll
      for (int c = 0; c < 4; ++c) {
        const int off = (((2 * c + (lg >> 1)) ^ (lm & 7)) << 3) + 4 * (lg & 1);
        bf16x4 vfr = *(const bf16x4*)&VtL[cb][rb + off];
        Oa[dt] = mfma16(pf[c], vfr, Oa[dt]);
      }
    }
  }

  // ---- epilogue: l-reduce over lg, redistribute inv, bounce via KsL[0] ----
  float s = psum;
  s += __shfl_xor(s, 16);
  s += __shfl_xor(s, 32);
  const float linv = 1.f / s;  // l(q=16w+lm), valid at all lg
  float invq[4];
#pragma unroll
  for (int r = 0; r < 4; ++r)
    invq[r] = __shfl(linv, 20 * lg + r);  // lane with lm = 4lg+r (same lg)
  __syncthreads();  // all KsL/VtL readers done; reuse KsL[0] as store bounce
#pragma unroll
  for (int dt = 0; dt < 4; ++dt)
#pragma unroll
    for (int r = 0; r < 4; ++r)
      KsL[0][(16 * wave + 4 * lg + r) * 64 + 16 * dt + lm] =
          f2bf(Oa[dt][r] * invq[r]);
  __syncthreads();
  {
    const int row = lane >> 2, seg = lane & 3;
    const uint4* src = (const uint4*)&KsL[0][(16 * wave + row) * 64 + seg * 16];
    uint4 v0 = src[0];
    uint4 v1 = src[1];
    u16* dst = yb + (size_t)(b * Tz + q0 + 16 * wave + row) * Cz + h * Dz + seg * 16;
    *(uint4*)dst = v0;
    *(uint4*)(dst + 8) = v1;
  }
}

extern "C" void kernel_launch(void* const* d_in, const int* in_sizes, int n_in,
                              void* d_out, int out_size, void* d_ws, size_t ws_size,
                              hipStream_t stream) {
  const float* x      = (const float*)d_in[0];
  const float* w_attn = (const float*)d_in[1];
  const float* b_attn = (const float*)d_in[2];
  const float* w_proj = (const float*)d_in[3];
  const float* b_proj = (const float*)d_in[4];

  char* ws = (char*)d_ws;
  u16* xb   = (u16*)(ws);                        //  8 MB: x bf16 [4096,1024]
  u16* waT  = (u16*)(ws + (8ull << 20));         //  6 MB: w_attn^T bf16 [3072,1024]
  u16* wpT  = (u16*)(ws + (14ull << 20));        //  2 MB: w_proj^T bf16 [1024,1024]
  u16* qkvb = (u16*)(ws + (16ull << 20));        // 24 MB: qkv bf16 (q pre-scaled; V cols unused)
  u16* yb   = (u16*)(ws + (40ull << 20));        //  8 MB: y bf16 [4096,1024]
  u16* vTt  = (u16*)(ws + (48ull << 20));        //  8 MB: V^T bf16 [2*16*64][2048]

  const int M = Bz * Tz;  // 4096

  prep_kernel<<<NCAST + NTA + 1024, 256, 0, stream>>>(x, w_attn, w_proj, xb, waT, wpT);
  gemm_bt<true, 128, true><<<dim3(3 * Cz / 128, M / 128), 256, 0, stream>>>(
      xb, waT, b_attn, qkvb, vTt, M, 3 * Cz, Cz, Cz, QSCALE);
  attn_kernel<<<1024, 256, 0, stream>>>(qkvb, vTt, yb);
  gemm_bt<false, 64, false><<<dim3(Cz / 64, M / 128), 256, 0, stream>>>(
      yb, wpT, b_proj, d_out, nullptr, M, Cz, Cz, 0, 1.f);
}